// Round 4
// baseline (199.949 us; speedup 1.0000x reference)
//
#include <hip/hip_runtime.h>

#define FL 9
#define CIN 16
#define COUT 16
#define T_IN 2048
#define T_OUT 2040
#define TTILE 64
#define XW (TTILE + FL - 1)  // 72

// grid = 1024 blocks: bid = b(1) | tile(5) | cinq(2) | coquad(2)
// block = 256 threads = 64 t-local x 4 cin-local (wave == one cin, uniform)
// Each thread: one (t, cin), 4 couts, all 9 taps.
// res = (Q + b)*P*Q*conj(P) * (a/|P|^2), P = qp + c, and
// P Q conj(P) = A2 pw^2 + A1 pw + A0 (A's c-independent), B = Q*A:
//   A2 = Q, A1 = (0, 2 v x u), A0 = (qw h, 2(v.u)v - h u), v=vec(qp), h=|v|^2
// res = ((B2 + bv A2) pw^2 + (B1 + bv A1) pw + (B0 + bv A0)) * (av/nsq).
__global__ __launch_bounds__(256, 4) void qconv_main(
    const float* __restrict__ x, const float* __restrict__ pa,
    const float* __restrict__ pb, const float* __restrict__ pc,
    float4* __restrict__ part)
{
    __shared__ float4 xs[4][XW];           // 4.5 KB
    __shared__ float4 pp[4][4][FL];        // [co_l][cin_l][j], 2304 B
    __shared__ float4 red[3][4][TTILE];    // 12 KB

    const int bid    = blockIdx.x;
    const int coquad = bid & 3;
    const int cinq   = (bid >> 2) & 3;
    const int tile   = (bid >> 4) & 31;
    const int b      = bid >> 9;
    const int t0     = tile * TTILE;

    const int tid = threadIdx.x;
    const int tl  = tid & 63;
    const int cl  = tid >> 6;              // wave index == cin-local
    const int cin = cinq * 4 + cl;
    const int cob = coquad * 4;

    // stage x window (each wave stages its own cin)
    {
        const float4* xg = (const float4*)x + (b * CIN + cin) * T_IN;
        for (int i = tl; i < XW; i += 64) {
            int t = t0 + i;
            if (t > T_IN - 1) t = T_IN - 1;  // clamped lanes feed only guarded-out t
            xs[cl][i] = xg[t];
        }
    }
    // stage params interleaved (a,b,c,0): 144 float4
    if (tid < 4 * 4 * FL) {
        const int co_l = tid / (4 * FL);
        const int r    = tid - co_l * (4 * FL);
        const int ci_l = r / FL;
        const int j    = r - ci_l * FL;
        const int pidx = ((cob + co_l) * CIN + (cinq * 4 + ci_l)) * FL + j;
        pp[co_l][ci_l][j] = make_float4(pa[pidx], pb[pidx], pc[pidx], 0.0f);
    }
    __syncthreads();

    // preload the 9-tap window into registers (static indices via full unroll)
    float4 q[FL];
    #pragma unroll
    for (int j = 0; j < FL; ++j) q[j] = xs[cl][tl + j];

    const float4 qp  = q[4];               // center tap j = FL/2
    const float  qpw = qp.x;
    const float  vx = qp.y, vy = qp.z, vz = qp.w;
    const float  h  = vx * vx + vy * vy + vz * vz;

    float4 acc[4];
    #pragma unroll
    for (int co = 0; co < 4; ++co) acc[co] = make_float4(0.f, 0.f, 0.f, 0.f);

    #pragma unroll
    for (int j = 0; j < FL; ++j) {
        const float qw = q[j].x, ux = q[j].y, uy = q[j].z, uz = q[j].w;

        // coefficient quaternions, shared across the 4 couts
        const float cx = vy * uz - vz * uy;      // v x u
        const float cy = vz * ux - vx * uz;
        const float cz = vx * uy - vy * ux;
        const float d  = vx * ux + vy * uy + vz * uz;
        const float uu = ux * ux + uy * uy + uz * uz;

        const float a1x = cx + cx, a1y = cy + cy, a1z = cz + cz;  // A1 vec
        const float d2  = d + d;
        const float a0w = qw * h;
        const float a0x = d2 * vx - h * ux;
        const float a0y = d2 * vy - h * uy;
        const float a0z = d2 * vz - h * uz;

        const float b2w = qw * qw - uu;          // B2 = Q^2
        const float q2  = qw + qw;
        const float b2x = q2 * ux, b2y = q2 * uy, b2z = q2 * uz;

        // B1 = hmul(Q, (0, A1)) = (-u.A1, qw A1 + u x A1)
        const float b1w = -(ux * a1x + uy * a1y + uz * a1z);
        const float b1x = qw * a1x + (uy * a1z - uz * a1y);
        const float b1y = qw * a1y + (uz * a1x - ux * a1z);
        const float b1z = qw * a1z + (ux * a1y - uy * a1x);

        // B0 = hmul(Q, A0)
        const float b0w = qw * a0w - (ux * a0x + uy * a0y + uz * a0z);
        const float b0x = qw * a0x + a0w * ux + (uy * a0z - uz * a0y);
        const float b0y = qw * a0y + a0w * uy + (uz * a0x - ux * a0z);
        const float b0z = qw * a0z + a0w * uz + (ux * a0y - uy * a0x);

        #pragma unroll
        for (int co = 0; co < 4; ++co) {
            const float4 p = pp[co][cl][j];      // broadcast ds_read_b128
            const float av = p.x, bv = p.y, cv = p.z;

            const float pw  = qpw + cv;
            const float p2  = pw * pw;
            const float nsq = p2 + h;
            float rn = __builtin_amdgcn_rcpf(nsq);
            rn = rn * (2.0f - nsq * rn);         // 1 Newton step
            const float s = av * rn;

            const float f2w = __builtin_fmaf(bv, qw, b2w);
            const float f2x = __builtin_fmaf(bv, ux, b2x);
            const float f2y = __builtin_fmaf(bv, uy, b2y);
            const float f2z = __builtin_fmaf(bv, uz, b2z);
            const float f1x = __builtin_fmaf(bv, a1x, b1x);
            const float f1y = __builtin_fmaf(bv, a1y, b1y);
            const float f1z = __builtin_fmaf(bv, a1z, b1z);
            const float f0w = __builtin_fmaf(bv, a0w, b0w);
            const float f0x = __builtin_fmaf(bv, a0x, b0x);
            const float f0y = __builtin_fmaf(bv, a0y, b0y);
            const float f0z = __builtin_fmaf(bv, a0z, b0z);

            // A1w == 0, so F1w == b1w
            const float rw = __builtin_fmaf(f2w, p2, __builtin_fmaf(b1w, pw, f0w));
            const float rx = __builtin_fmaf(f2x, p2, __builtin_fmaf(f1x, pw, f0x));
            const float ry = __builtin_fmaf(f2y, p2, __builtin_fmaf(f1y, pw, f0y));
            const float rz = __builtin_fmaf(f2z, p2, __builtin_fmaf(f1z, pw, f0z));

            acc[co].x = __builtin_fmaf(rw, s, acc[co].x);
            acc[co].y = __builtin_fmaf(rx, s, acc[co].y);
            acc[co].z = __builtin_fmaf(ry, s, acc[co].z);
            acc[co].w = __builtin_fmaf(rz, s, acc[co].w);
        }
    }

    // cross-cin (4-way) reduce within block via LDS
    if (cl != 0) {
        #pragma unroll
        for (int co = 0; co < 4; ++co) red[cl - 1][co][tl] = acc[co];
    }
    __syncthreads();
    if (cl == 0) {
        const int t = t0 + tl;
        if (t < T_OUT) {
            #pragma unroll
            for (int co = 0; co < 4; ++co) {
                const float4 r0 = red[0][co][tl];
                const float4 r1 = red[1][co][tl];
                const float4 r2 = red[2][co][tl];
                float4 o;
                o.x = acc[co].x + r0.x + r1.x + r2.x;
                o.y = acc[co].y + r0.y + r1.y + r2.y;
                o.z = acc[co].z + r0.z + r1.z + r2.z;
                o.w = acc[co].w + r0.w + r1.w + r2.w;
                part[(cinq * 32 + b * 16 + cob + co) * 2048 + t] = o;
            }
        }
    }
}

// sum the 4 cin-quarter partials -> d_out
__global__ __launch_bounds__(256) void qconv_reduce(
    const float4* __restrict__ part, float4* __restrict__ out)
{
    const int N = 2 * COUT * T_OUT;  // 65280 float4s
    for (int i = blockIdx.x * 256 + threadIdx.x; i < N; i += gridDim.x * 256) {
        const int t  = i % T_OUT;
        const int bc = i / T_OUT;    // b*16 + co
        const float4 p0 = part[(0 * 32 + bc) * 2048 + t];
        const float4 p1 = part[(1 * 32 + bc) * 2048 + t];
        const float4 p2 = part[(2 * 32 + bc) * 2048 + t];
        const float4 p3 = part[(3 * 32 + bc) * 2048 + t];
        float4 o;
        o.x = (p0.x + p1.x) + (p2.x + p3.x);
        o.y = (p0.y + p1.y) + (p2.y + p3.y);
        o.z = (p0.z + p1.z) + (p2.z + p3.z);
        o.w = (p0.w + p1.w) + (p2.w + p3.w);
        out[i] = o;
    }
}

extern "C" void kernel_launch(void* const* d_in, const int* in_sizes, int n_in,
                              void* d_out, int out_size, void* d_ws, size_t ws_size,
                              hipStream_t stream) {
    const float* x  = (const float*)d_in[0];
    const float* pa = (const float*)d_in[1];
    const float* pb = (const float*)d_in[2];
    const float* pc = (const float*)d_in[3];
    float4* part = (float4*)d_ws;     // 4 x 32 x 2048 float4 = 4 MB
    float4* out  = (float4*)d_out;

    qconv_main<<<dim3(1024), dim3(256), 0, stream>>>(x, pa, pb, pc, part);
    qconv_reduce<<<dim3(256), dim3(256), 0, stream>>>(part, out);
}

// Round 5
// 74.901 us; speedup vs baseline: 2.6695x; 2.6695x over previous
//
#include <hip/hip_runtime.h>

#define FL 9
#define CIN 16
#define COUT 16
#define T_IN 2048
#define T_OUT 2040
#define TTILE 64
#define XW (TTILE + FL - 1)  // 72

// grid = 1024 blocks: bid = b(1) | tile(5) | cinq(2) | coquad(2)
// block = 256 threads = 64 t-local x 4 cin-local (wave == one cin, uniform)
// Each thread: one (t, cin), 4 couts, all 9 taps.
// res = (Q + b)*P*Q*conj(P) * (a/|P|^2), P = qp + c, and
// P Q conj(P) = A2 pw^2 + A1 pw + A0 (A's c-independent), B = Q*A:
//   A2 = Q, A1 = (0, 2 v x u), A0 = (qw h, 2(v.u)v - h u), v=vec(qp), h=|v|^2
// res = ((B2 + bv A2) pw^2 + (B1 + bv A1) pw + (B0 + bv A0)) * (av/nsq).
//
// __launch_bounds__(256,2): empirically arg maps to VGPR cap = 256/arg on this
// compiler ((256,4) gave 64 VGPR + 242 MB spills in round 4). Target: 128 cap,
// 4 waves/SIMD, zero spill.
__global__ __launch_bounds__(256, 2) void qconv_main(
    const float* __restrict__ x, const float* __restrict__ pa,
    const float* __restrict__ pb, const float* __restrict__ pc,
    float4* __restrict__ part)
{
    __shared__ float4 xs[4][XW];           // 4.5 KB
    __shared__ float4 pp[4][4][FL];        // [co_l][cin_l][j], 2304 B
    __shared__ float4 red[3][4][TTILE];    // 12 KB

    const int bid    = blockIdx.x;
    const int coquad = bid & 3;
    const int cinq   = (bid >> 2) & 3;
    const int tile   = (bid >> 4) & 31;
    const int b      = bid >> 9;
    const int t0     = tile * TTILE;

    const int tid = threadIdx.x;
    const int tl  = tid & 63;
    const int cl  = tid >> 6;              // wave index == cin-local
    const int cin = cinq * 4 + cl;
    const int cob = coquad * 4;

    // stage x window (each wave stages its own cin)
    {
        const float4* xg = (const float4*)x + (b * CIN + cin) * T_IN;
        for (int i = tl; i < XW; i += 64) {
            int t = t0 + i;
            if (t > T_IN - 1) t = T_IN - 1;  // clamped lanes feed only guarded-out t
            xs[cl][i] = xg[t];
        }
    }
    // stage params interleaved (a,b,c,0): 144 float4
    if (tid < 4 * 4 * FL) {
        const int co_l = tid / (4 * FL);
        const int r    = tid - co_l * (4 * FL);
        const int ci_l = r / FL;
        const int j    = r - ci_l * FL;
        const int pidx = ((cob + co_l) * CIN + (cinq * 4 + ci_l)) * FL + j;
        pp[co_l][ci_l][j] = make_float4(pa[pidx], pb[pidx], pc[pidx], 0.0f);
    }
    __syncthreads();

    const float4 qp  = xs[cl][tl + 4];     // center tap j = FL/2
    const float  qpw = qp.x;
    const float  vx = qp.y, vy = qp.z, vz = qp.w;
    const float  h  = vx * vx + vy * vy + vz * vz;

    float4 acc[4];
    #pragma unroll
    for (int co = 0; co < 4; ++co) acc[co] = make_float4(0.f, 0.f, 0.f, 0.f);

    #pragma unroll
    for (int j = 0; j < FL; ++j) {
        const float4 Q = xs[cl][tl + j];   // per-tap LDS read (low reg pressure)
        const float qw = Q.x, ux = Q.y, uy = Q.z, uz = Q.w;

        // coefficient quaternions, shared across the 4 couts
        const float cx = vy * uz - vz * uy;      // v x u
        const float cy = vz * ux - vx * uz;
        const float cz = vx * uy - vy * ux;
        const float d  = vx * ux + vy * uy + vz * uz;
        const float uu = ux * ux + uy * uy + uz * uz;

        const float a1x = cx + cx, a1y = cy + cy, a1z = cz + cz;  // A1 vec
        const float d2  = d + d;
        const float a0w = qw * h;
        const float a0x = d2 * vx - h * ux;
        const float a0y = d2 * vy - h * uy;
        const float a0z = d2 * vz - h * uz;

        const float b2w = qw * qw - uu;          // B2 = Q^2
        const float q2  = qw + qw;
        const float b2x = q2 * ux, b2y = q2 * uy, b2z = q2 * uz;

        // B1 = hmul(Q, (0, A1)) = (-u.A1, qw A1 + u x A1)
        const float b1w = -(ux * a1x + uy * a1y + uz * a1z);
        const float b1x = qw * a1x + (uy * a1z - uz * a1y);
        const float b1y = qw * a1y + (uz * a1x - ux * a1z);
        const float b1z = qw * a1z + (ux * a1y - uy * a1x);

        // B0 = hmul(Q, A0)
        const float b0w = qw * a0w - (ux * a0x + uy * a0y + uz * a0z);
        const float b0x = qw * a0x + a0w * ux + (uy * a0z - uz * a0y);
        const float b0y = qw * a0y + a0w * uy + (uz * a0x - ux * a0z);
        const float b0z = qw * a0z + a0w * uz + (ux * a0y - uy * a0x);

        #pragma unroll
        for (int co = 0; co < 4; ++co) {
            const float4 p = pp[co][cl][j];      // broadcast ds_read_b128
            const float av = p.x, bv = p.y, cv = p.z;

            const float pw  = qpw + cv;
            const float p2  = pw * pw;
            const float nsq = p2 + h;
            float rn = __builtin_amdgcn_rcpf(nsq);
            rn = rn * (2.0f - nsq * rn);         // 1 Newton step
            const float s = av * rn;

            const float f2w = __builtin_fmaf(bv, qw, b2w);
            const float f2x = __builtin_fmaf(bv, ux, b2x);
            const float f2y = __builtin_fmaf(bv, uy, b2y);
            const float f2z = __builtin_fmaf(bv, uz, b2z);
            const float f1x = __builtin_fmaf(bv, a1x, b1x);
            const float f1y = __builtin_fmaf(bv, a1y, b1y);
            const float f1z = __builtin_fmaf(bv, a1z, b1z);
            const float f0w = __builtin_fmaf(bv, a0w, b0w);
            const float f0x = __builtin_fmaf(bv, a0x, b0x);
            const float f0y = __builtin_fmaf(bv, a0y, b0y);
            const float f0z = __builtin_fmaf(bv, a0z, b0z);

            // A1w == 0, so F1w == b1w
            const float rw = __builtin_fmaf(f2w, p2, __builtin_fmaf(b1w, pw, f0w));
            const float rx = __builtin_fmaf(f2x, p2, __builtin_fmaf(f1x, pw, f0x));
            const float ry = __builtin_fmaf(f2y, p2, __builtin_fmaf(f1y, pw, f0y));
            const float rz = __builtin_fmaf(f2z, p2, __builtin_fmaf(f1z, pw, f0z));

            acc[co].x = __builtin_fmaf(rw, s, acc[co].x);
            acc[co].y = __builtin_fmaf(rx, s, acc[co].y);
            acc[co].z = __builtin_fmaf(ry, s, acc[co].z);
            acc[co].w = __builtin_fmaf(rz, s, acc[co].w);
        }
    }

    // cross-cin (4-way) reduce within block via LDS
    if (cl != 0) {
        #pragma unroll
        for (int co = 0; co < 4; ++co) red[cl - 1][co][tl] = acc[co];
    }
    __syncthreads();
    if (cl == 0) {
        const int t = t0 + tl;
        if (t < T_OUT) {
            #pragma unroll
            for (int co = 0; co < 4; ++co) {
                const float4 r0 = red[0][co][tl];
                const float4 r1 = red[1][co][tl];
                const float4 r2 = red[2][co][tl];
                float4 o;
                o.x = acc[co].x + r0.x + r1.x + r2.x;
                o.y = acc[co].y + r0.y + r1.y + r2.y;
                o.z = acc[co].z + r0.z + r1.z + r2.z;
                o.w = acc[co].w + r0.w + r1.w + r2.w;
                part[(cinq * 32 + b * 16 + cob + co) * 2048 + t] = o;
            }
        }
    }
}

// sum the 4 cin-quarter partials -> d_out
__global__ __launch_bounds__(256) void qconv_reduce(
    const float4* __restrict__ part, float4* __restrict__ out)
{
    const int N = 2 * COUT * T_OUT;  // 65280 float4s
    for (int i = blockIdx.x * 256 + threadIdx.x; i < N; i += gridDim.x * 256) {
        const int t  = i % T_OUT;
        const int bc = i / T_OUT;    // b*16 + co
        const float4 p0 = part[(0 * 32 + bc) * 2048 + t];
        const float4 p1 = part[(1 * 32 + bc) * 2048 + t];
        const float4 p2 = part[(2 * 32 + bc) * 2048 + t];
        const float4 p3 = part[(3 * 32 + bc) * 2048 + t];
        float4 o;
        o.x = (p0.x + p1.x) + (p2.x + p3.x);
        o.y = (p0.y + p1.y) + (p2.y + p3.y);
        o.z = (p0.z + p1.z) + (p2.z + p3.z);
        o.w = (p0.w + p1.w) + (p2.w + p3.w);
        out[i] = o;
    }
}

extern "C" void kernel_launch(void* const* d_in, const int* in_sizes, int n_in,
                              void* d_out, int out_size, void* d_ws, size_t ws_size,
                              hipStream_t stream) {
    const float* x  = (const float*)d_in[0];
    const float* pa = (const float*)d_in[1];
    const float* pb = (const float*)d_in[2];
    const float* pc = (const float*)d_in[3];
    float4* part = (float4*)d_ws;     // 4 x 32 x 2048 float4 = 4 MB
    float4* out  = (float4*)d_out;

    qconv_main<<<dim3(1024), dim3(256), 0, stream>>>(x, pa, pb, pc, part);
    qconv_reduce<<<dim3(256), dim3(256), 0, stream>>>(part, out);
}